// Round 1
// baseline (696.699 us; speedup 1.0000x reference)
//
#include <hip/hip_runtime.h>

#define N_PIX 1024

// ---------------------------------------------------------------------------
// Quaternion 1x1 conv as Hamilton-structured GEMM.
// x: [B, Cin_total, 4, 1024] (view via xbs batch stride, channel 0 at ptr)
// w: [4, Cout, Cin] (1x1), bias: [Cout,4] or null
// y: [B, Cout_total, 4, 1024] via ybs
// grid: (B*32, Cout/32), block 256.  Tile: 32 pixels x 32 out-channels.
// ---------------------------------------------------------------------------
__global__ __launch_bounds__(256) void qconv1x1_kernel(
    const float* __restrict__ x, int xbs,
    const float* __restrict__ w,
    const float* __restrict__ bias,
    float* __restrict__ y, int ybs,
    int Cin, int Cout)
{
    __shared__ float xs[32 * 4 * 32];   // [ci][qc][p] 16 KiB
    const int tid = threadIdx.x;
    const int p   = tid & 31;
    const int j   = tid >> 5;                 // 0..7
    const int b   = blockIdx.x >> 5;
    const int p0  = (blockIdx.x & 31) << 5;
    const int coB = blockIdx.y << 5;

    float acc[4][4];
#pragma unroll
    for (int t = 0; t < 4; t++)
#pragma unroll
        for (int c = 0; c < 4; c++) acc[t][c] = 0.f;

    const float* xb  = x + (size_t)b * xbs + p0;
    const int    wqs = Cout * Cin;

    for (int c0 = 0; c0 < Cin; c0 += 32) {
        __syncthreads();
#pragma unroll
        for (int i = 0; i < 16; i++) {
            int flat = i * 256 + tid;
            int ci   = flat >> 7;        // 0..31
            int r    = flat & 127;       // qc*32 + p
            xs[flat] = xb[(size_t)(c0 + ci) * 4 * N_PIX + (r >> 5) * N_PIX + (r & 31)];
        }
        __syncthreads();

        for (int ci = 0; ci < 32; ci++) {
            float xr = xs[ci * 128 + 0 * 32 + p];
            float xi = xs[ci * 128 + 1 * 32 + p];
            float xj = xs[ci * 128 + 2 * 32 + p];
            float xk = xs[ci * 128 + 3 * 32 + p];
#pragma unroll
            for (int t = 0; t < 4; t++) {
                int co = coB + j * 4 + t;
                const float* wp = w + (size_t)co * Cin + c0 + ci;
                float wr = wp[0], wi = wp[wqs], wj2 = wp[2 * wqs], wk = wp[3 * wqs];
                acc[t][0] += xr * wr - xi * wi  - xj * wj2 - xk * wk;
                acc[t][1] += xr * wi + xi * wr  + xj * wk  - xk * wj2;
                acc[t][2] += xr * wj2 - xi * wk + xj * wr  + xk * wi;
                acc[t][3] += xr * wk + xi * wj2 - xj * wi  + xk * wr;
            }
        }
    }

#pragma unroll
    for (int t = 0; t < 4; t++) {
        int co = coB + j * 4 + t;
#pragma unroll
        for (int c = 0; c < 4; c++) {
            float v = acc[t][c];
            if (bias) v += bias[co * 4 + c];
            y[(size_t)b * ybs + ((size_t)co * 4 + c) * N_PIX + p0 + p] = v;
        }
    }
}

// ---------------------------------------------------------------------------
// IQBN stats: one block per (c,qc). sums over B=4 batches * 1024 pixels.
// stats[cq*2] = mean, stats[cq*2+1] = rsqrt(var+eps)
// ---------------------------------------------------------------------------
__global__ __launch_bounds__(256) void iqbn_stats_kernel(
    const float* __restrict__ x, int xbs, float* __restrict__ stats)
{
    const int cq = blockIdx.x;
    float s = 0.f, s2 = 0.f;
#pragma unroll
    for (int b = 0; b < 4; b++) {
        const float* xp = x + (size_t)b * xbs + (size_t)cq * N_PIX;
        for (int p = threadIdx.x; p < N_PIX; p += 256) {
            float v = xp[p];
            s += v; s2 += v * v;
        }
    }
#pragma unroll
    for (int o = 32; o > 0; o >>= 1) {
        s  += __shfl_down(s, o);
        s2 += __shfl_down(s2, o);
    }
    __shared__ float red[8];
    int wid = threadIdx.x >> 6, lane = threadIdx.x & 63;
    if (lane == 0) { red[wid * 2] = s; red[wid * 2 + 1] = s2; }
    __syncthreads();
    if (threadIdx.x == 0) {
        s = 0.f; s2 = 0.f;
#pragma unroll
        for (int i = 0; i < 4; i++) { s += red[2 * i]; s2 += red[2 * i + 1]; }
        const float inv = 1.0f / 4096.0f;
        float mean = s * inv;
        float var  = s2 * inv - mean * mean;
        stats[cq * 2]     = mean;
        stats[cq * 2 + 1] = rsqrtf(var + 1e-5f);
    }
}

// ---------------------------------------------------------------------------
// IQBN apply (+optional relu). One block per (b, cq); 256 threads = 256 float4.
// ---------------------------------------------------------------------------
__global__ __launch_bounds__(256) void iqbn_apply_kernel(
    const float* __restrict__ x, int xbs,
    float* __restrict__ y, int ybs,
    const float* __restrict__ stats,
    const float* __restrict__ g, const float* __restrict__ bta,
    int C4, int relu)
{
    int cq = blockIdx.x % C4;
    int b  = blockIdx.x / C4;
    float mean = stats[cq * 2], rstd = stats[cq * 2 + 1];
    float ga = g[cq] * rstd;
    float bb = bta[cq] - mean * ga;
    const float4* xp = (const float4*)(x + (size_t)b * xbs + (size_t)cq * N_PIX);
    float4*       yp = (float4*)(y + (size_t)b * ybs + (size_t)cq * N_PIX);
    float4 v = xp[threadIdx.x];
    v.x = v.x * ga + bb; v.y = v.y * ga + bb; v.z = v.z * ga + bb; v.w = v.w * ga + bb;
    if (relu) {
        v.x = fmaxf(v.x, 0.f); v.y = fmaxf(v.y, 0.f);
        v.z = fmaxf(v.z, 0.f); v.w = fmaxf(v.w, 0.f);
    }
    yp[threadIdx.x] = v;
}

// ---------------------------------------------------------------------------
// Attention for one (b, head, qcomp) group; d=16, N=1024.
// qkv: [B,192,4,1024] (head-major channel split q:0-15 k:16-31 v:32-47)
// o:   [B,64,4,1024]
// grid: (64, 4)  block 256: thread = one n row; K/V staged in 512-m LDS tiles.
// ---------------------------------------------------------------------------
__global__ __launch_bounds__(256) void qattn_kernel(
    const float* __restrict__ qkv, float* __restrict__ o)
{
    __shared__ float ks[512 * 20];   // [m][d] pad to 20 for aligned b128
    __shared__ float vs[512 * 20];
    const int grp = blockIdx.x;
    const int qc = grp & 3, hd = (grp >> 2) & 3, b = grp >> 4;
    const int n  = (blockIdx.y << 8) + threadIdx.x;
    const float* base = qkv + ((size_t)(b * 192 + hd * 48) * 4) * N_PIX;

    float q[16];
#pragma unroll
    for (int d = 0; d < 16; d++)
        q[d] = base[((size_t)d * 4 + qc) * N_PIX + n] * 0.25f;   // fold 1/sqrt(16)

    float M = -1e30f, L = 0.f;
    float acc[16];
#pragma unroll
    for (int d = 0; d < 16; d++) acc[d] = 0.f;

    for (int t = 0; t < 2; t++) {
        const int m0 = t << 9;
        __syncthreads();
#pragma unroll
        for (int i = 0; i < 32; i++) {
            int flat = i * 256 + threadIdx.x;
            int d = flat >> 9, m = flat & 511;
            ks[m * 20 + d] = base[((size_t)(16 + d) * 4 + qc) * N_PIX + m0 + m];
            vs[m * 20 + d] = base[((size_t)(32 + d) * 4 + qc) * N_PIX + m0 + m];
        }
        __syncthreads();

        for (int m = 0; m < 512; m++) {
            const float* kp = &ks[m * 20];
            float s = 0.f;
#pragma unroll
            for (int d = 0; d < 16; d++) s += q[d] * kp[d];
            float nM = fmaxf(M, s);
            float r  = __expf(M - nM);
            float e  = __expf(s - nM);
            L = L * r + e;
            M = nM;
            const float* vp = &vs[m * 20];
#pragma unroll
            for (int d = 0; d < 16; d++) acc[d] = acc[d] * r + e * vp[d];
        }
    }
    float inv = 1.f / L;
    float* ob = o + ((size_t)(b * 64 + hd * 16) * 4 + qc) * N_PIX + n;
#pragma unroll
    for (int d = 0; d < 16; d++) ob[(size_t)d * 4096] = acc[d] * inv;
}

// ---------------------------------------------------------------------------
// 3x3 grouped quaternion conv (groups=16, Cin/g=Cout/g=4) + residual add.
// x: [4,64,4,32,32] ; w: [4,64,4,3,3] ; bias [64,4] ; y = x + conv(x)
// grid 1024 = (b, co, ptile) ; block 256 = pixels.
// ---------------------------------------------------------------------------
__global__ __launch_bounds__(256) void pe_conv_kernel(
    const float* __restrict__ x,
    const float* __restrict__ w,
    const float* __restrict__ bias,
    float* __restrict__ y)
{
    const int bid = blockIdx.x;
    const int pt = bid & 3, co = (bid >> 2) & 63, b = bid >> 8;
    const int p = (pt << 8) + threadIdx.x;
    const int hh = p >> 5, ww = p & 31;
    const int g4 = (co >> 2) << 2;

    float a0 = bias[co * 4 + 0], a1 = bias[co * 4 + 1];
    float a2 = bias[co * 4 + 2], a3 = bias[co * 4 + 3];
    const float* xb = x + (size_t)b * 64 * 4096;
    const float* wb = w + co * 36;

#pragma unroll
    for (int dy = 0; dy < 3; dy++) {
        int yy = hh + dy - 1;
        if ((unsigned)yy >= 32u) continue;
#pragma unroll
        for (int dx = 0; dx < 3; dx++) {
            int xx = ww + dx - 1;
            if ((unsigned)xx >= 32u) continue;
            int sp = yy * 32 + xx;
#pragma unroll
            for (int cl = 0; cl < 4; cl++) {
                const float* xp = xb + (size_t)(g4 + cl) * 4096 + sp;
                float xr = xp[0], xi = xp[1024], xj = xp[2048], xk = xp[3072];
                const float* wp = wb + cl * 9 + dy * 3 + dx;
                float wr = wp[0], wi = wp[2304], wj2 = wp[4608], wk = wp[6912];
                a0 += xr * wr - xi * wi  - xj * wj2 - xk * wk;
                a1 += xr * wi + xi * wr  + xj * wk  - xk * wj2;
                a2 += xr * wj2 - xi * wk + xj * wr  + xk * wi;
                a3 += xr * wk + xi * wj2 - xj * wi  + xk * wr;
            }
        }
    }
    size_t ob = (size_t)b * 64 * 4096 + (size_t)co * 4096 + p;
    y[ob]        = x[ob]        + a0;
    y[ob + 1024] = x[ob + 1024] + a1;
    y[ob + 2048] = x[ob + 2048] + a2;
    y[ob + 3072] = x[ob + 3072] + a3;
}

// ---------------------------------------------------------------------------
extern "C" void kernel_launch(void* const* d_in, const int* in_sizes, int n_in,
                              void* d_out, int out_size, void* d_ws, size_t ws_size,
                              hipStream_t stream)
{
    const float* x      = (const float*)d_in[0];
    const float* cv1_w  = (const float*)d_in[1];
    const float* bn1_g  = (const float*)d_in[2];
    const float* bn1_b  = (const float*)d_in[3];
    const float* qkv_w  = (const float*)d_in[4];
    const float* qkv_b  = (const float*)d_in[5];
    const float* proj_w = (const float*)d_in[6];
    const float* proj_b = (const float*)d_in[7];
    const float* pe_w   = (const float*)d_in[8];
    const float* pe_b   = (const float*)d_in[9];
    const float* ang    = (const float*)d_in[10];
    const float* anb    = (const float*)d_in[11];
    const float* ffn1_w = (const float*)d_in[12];
    const float* fbn1_g = (const float*)d_in[13];
    const float* fbn1_b = (const float*)d_in[14];
    const float* ffn2_w = (const float*)d_in[15];
    const float* fbn2_g = (const float*)d_in[16];
    const float* fbn2_b = (const float*)d_in[17];
    const float* cv2_w  = (const float*)d_in[18];
    const float* bn2_g  = (const float*)d_in[19];
    const float* bn2_b  = (const float*)d_in[20];
    float* out = (float*)d_out;

    float* ws    = (float*)d_ws;
    float* hbuf  = ws;                                  // [4,128,4,1024] persist (b-half + a2)
    float* qkvb  = ws + 2097152;                        // [4,192,4,1024]
    float* bufA  = ws + 2097152 + 3145728;              // [4,64,4,1024]
    float* bufD  = bufA + 1048576;                      // [4,128,4,1024]
    float* stats = bufD + 2097152;                      // 1024 floats
    float* bufB  = qkvb;                                // alias (qkv dead after attn)
    float* bufC  = qkvb + 1048576;                      // alias
    float* cv2o  = qkvb;                                // alias (2M floats)

    const int S128 = 128 * 4096, S192 = 192 * 4096, S64 = 64 * 4096;

    // 1. cv1 + iqbn + relu -> hbuf
    qconv1x1_kernel<<<dim3(128, 4), 256, 0, stream>>>(x, S128, cv1_w, nullptr, hbuf, S128, 128, 128);
    iqbn_stats_kernel<<<512, 256, 0, stream>>>(hbuf, S128, stats);
    iqbn_apply_kernel<<<2048, 256, 0, stream>>>(hbuf, S128, hbuf, S128, stats, bn1_g, bn1_b, 512, 1);

    // 2. qkv conv (a = hbuf[:, :64]) -> qkvb
    qconv1x1_kernel<<<dim3(128, 6), 256, 0, stream>>>(hbuf, S128, qkv_w, qkv_b, qkvb, S192, 64, 192);

    // 3. attention -> bufA
    qattn_kernel<<<dim3(64, 4), 256, 0, stream>>>(qkvb, bufA);

    // 4. pe conv + residual -> bufB
    pe_conv_kernel<<<1024, 256, 0, stream>>>(bufA, pe_w, pe_b, bufB);

    // 5. proj conv -> bufC ; iqbn (no relu) in place
    qconv1x1_kernel<<<dim3(128, 2), 256, 0, stream>>>(bufB, S64, proj_w, proj_b, bufC, S64, 64, 64);
    iqbn_stats_kernel<<<256, 256, 0, stream>>>(bufC, S64, stats);
    iqbn_apply_kernel<<<1024, 256, 0, stream>>>(bufC, S64, bufC, S64, stats, ang, anb, 256, 0);

    // 6. ffn1 -> bufD ; iqbn + relu in place
    qconv1x1_kernel<<<dim3(128, 4), 256, 0, stream>>>(bufC, S64, ffn1_w, nullptr, bufD, S128, 64, 128);
    iqbn_stats_kernel<<<512, 256, 0, stream>>>(bufD, S128, stats);
    iqbn_apply_kernel<<<2048, 256, 0, stream>>>(bufD, S128, bufD, S128, stats, fbn1_g, fbn1_b, 512, 1);

    // 7. ffn2 -> bufA ; iqbn -> hbuf[:, :64]  (concat is free: b-half already at ch 64..127)
    qconv1x1_kernel<<<dim3(128, 2), 256, 0, stream>>>(bufD, S128, ffn2_w, nullptr, bufA, S64, 128, 64);
    iqbn_stats_kernel<<<256, 256, 0, stream>>>(bufA, S64, stats);
    iqbn_apply_kernel<<<1024, 256, 0, stream>>>(bufA, S64, hbuf, S128, stats, fbn2_g, fbn2_b, 256, 0);

    // 8. cv2 -> cv2o ; iqbn + relu -> out
    qconv1x1_kernel<<<dim3(128, 4), 256, 0, stream>>>(hbuf, S128, cv2_w, nullptr, cv2o, S128, 128, 128);
    iqbn_stats_kernel<<<512, 256, 0, stream>>>(cv2o, S128, stats);
    iqbn_apply_kernel<<<2048, 256, 0, stream>>>(cv2o, S128, out, S128, stats, bn2_g, bn2_b, 512, 1);
}

// Round 2
// 607.813 us; speedup vs baseline: 1.1462x; 1.1462x over previous
//
#include <hip/hip_runtime.h>

#define N_PIX 1024

// ---------------------------------------------------------------------------
// Weight prep: w[4][Cout][Cin] -> wt[Cin][Cout][4]  (coalesced staging later)
// ---------------------------------------------------------------------------
__global__ __launch_bounds__(256) void wprep_kernel(
    const float* __restrict__ w, float* __restrict__ wt, int Cout, int Cin)
{
    int idx = blockIdx.x * 256 + threadIdx.x;
    if (idx >= Cout * Cin) return;
    int ci = idx % Cin, co = idx / Cin;
    int qs = Cout * Cin;
    float4 v = make_float4(w[idx], w[qs + idx], w[2 * qs + idx], w[3 * qs + idx]);
    *(float4*)&wt[((size_t)ci * Cout + co) * 4] = v;
}

// ---------------------------------------------------------------------------
// Quaternion 1x1 conv as Hamilton-structured GEMM, LDS-staged x AND w tiles.
// x: [B, Cin_total, 4, 1024] via xbs; wt: [Cin][Cout][4]; y via ybs.
// grid: (B*32, Cout/32), block 256.  Tile: 32 pixels x 32 out-channels.
// ---------------------------------------------------------------------------
__global__ __launch_bounds__(256) void qconv1x1_kernel(
    const float* __restrict__ x, int xbs,
    const float* __restrict__ wt,
    const float* __restrict__ bias,
    float* __restrict__ y, int ybs,
    int Cin, int Cout)
{
    __shared__ float xs[4096];    // [ci][qc][p]        16 KiB
    __shared__ float wsm[4096];   // [ci][co_l*4+comp]  16 KiB
    const int tid = threadIdx.x;
    const int p   = tid & 31;
    const int j   = tid >> 5;                 // 0..7
    const int b   = blockIdx.x >> 5;
    const int p0  = (blockIdx.x & 31) << 5;
    const int coB = blockIdx.y << 5;

    float acc[4][4];
#pragma unroll
    for (int t = 0; t < 4; t++)
#pragma unroll
        for (int c = 0; c < 4; c++) acc[t][c] = 0.f;

    const float* xb = x + (size_t)b * xbs + p0;

    for (int c0 = 0; c0 < Cin; c0 += 32) {
        __syncthreads();
#pragma unroll
        for (int i = 0; i < 16; i++) {
            int flat = i * 256 + tid;
            int ci   = flat >> 7;        // 0..31
            int r    = flat & 127;
            xs[flat]  = xb[(size_t)(c0 + ci) * 4 * N_PIX + (r >> 5) * N_PIX + (r & 31)];
            wsm[flat] = wt[(size_t)(c0 + ci) * Cout * 4 + coB * 4 + r];
        }
        __syncthreads();

#pragma unroll 4
        for (int ci = 0; ci < 32; ci++) {
            float xr = xs[ci * 128 + p];
            float xi = xs[ci * 128 + 32 + p];
            float xj = xs[ci * 128 + 64 + p];
            float xk = xs[ci * 128 + 96 + p];
            const float* wrow = &wsm[ci * 128 + j * 16];
#pragma unroll
            for (int t = 0; t < 4; t++) {
                float4 wv = *(const float4*)(wrow + t * 4);
                acc[t][0] += xr * wv.x - xi * wv.y - xj * wv.z - xk * wv.w;
                acc[t][1] += xr * wv.y + xi * wv.x + xj * wv.w - xk * wv.z;
                acc[t][2] += xr * wv.z - xi * wv.w + xj * wv.x + xk * wv.y;
                acc[t][3] += xr * wv.w + xi * wv.z - xj * wv.y + xk * wv.x;
            }
        }
    }

#pragma unroll
    for (int t = 0; t < 4; t++) {
        int co = coB + j * 4 + t;
#pragma unroll
        for (int c = 0; c < 4; c++) {
            float v = acc[t][c];
            if (bias) v += bias[co * 4 + c];
            y[(size_t)b * ybs + ((size_t)co * 4 + c) * N_PIX + p0 + p] = v;
        }
    }
}

// ---------------------------------------------------------------------------
// IQBN stats: one block per (c,qc).
// ---------------------------------------------------------------------------
__global__ __launch_bounds__(256) void iqbn_stats_kernel(
    const float* __restrict__ x, int xbs, float* __restrict__ stats)
{
    const int cq = blockIdx.x;
    float s = 0.f, s2 = 0.f;
#pragma unroll
    for (int b = 0; b < 4; b++) {
        const float* xp = x + (size_t)b * xbs + (size_t)cq * N_PIX;
        for (int p = threadIdx.x; p < N_PIX; p += 256) {
            float v = xp[p];
            s += v; s2 += v * v;
        }
    }
#pragma unroll
    for (int o = 32; o > 0; o >>= 1) {
        s  += __shfl_down(s, o);
        s2 += __shfl_down(s2, o);
    }
    __shared__ float red[8];
    int wid = threadIdx.x >> 6, lane = threadIdx.x & 63;
    if (lane == 0) { red[wid * 2] = s; red[wid * 2 + 1] = s2; }
    __syncthreads();
    if (threadIdx.x == 0) {
        s = 0.f; s2 = 0.f;
#pragma unroll
        for (int i = 0; i < 4; i++) { s += red[2 * i]; s2 += red[2 * i + 1]; }
        const float inv = 1.0f / 4096.0f;
        float mean = s * inv;
        float var  = s2 * inv - mean * mean;
        stats[cq * 2]     = mean;
        stats[cq * 2 + 1] = rsqrtf(var + 1e-5f);
    }
}

// ---------------------------------------------------------------------------
// IQBN apply (+optional relu).
// ---------------------------------------------------------------------------
__global__ __launch_bounds__(256) void iqbn_apply_kernel(
    const float* __restrict__ x, int xbs,
    float* __restrict__ y, int ybs,
    const float* __restrict__ stats,
    const float* __restrict__ g, const float* __restrict__ bta,
    int C4, int relu)
{
    int cq = blockIdx.x % C4;
    int b  = blockIdx.x / C4;
    float mean = stats[cq * 2], rstd = stats[cq * 2 + 1];
    float ga = g[cq] * rstd;
    float bb = bta[cq] - mean * ga;
    const float4* xp = (const float4*)(x + (size_t)b * xbs + (size_t)cq * N_PIX);
    float4*       yp = (float4*)(y + (size_t)b * ybs + (size_t)cq * N_PIX);
    float4 v = xp[threadIdx.x];
    v.x = v.x * ga + bb; v.y = v.y * ga + bb; v.z = v.z * ga + bb; v.w = v.w * ga + bb;
    if (relu) {
        v.x = fmaxf(v.x, 0.f); v.y = fmaxf(v.y, 0.f);
        v.z = fmaxf(v.z, 0.f); v.w = fmaxf(v.w, 0.f);
    }
    yp[threadIdx.x] = v;
}

// ---------------------------------------------------------------------------
// Attention, batched online softmax (m-chunks of 8 for ILP).
// qkv: [B,192,4,1024]; o: [B,64,4,1024]; grid (64,4), block 256.
// ---------------------------------------------------------------------------
__global__ __launch_bounds__(256) void qattn_kernel(
    const float* __restrict__ qkv, float* __restrict__ o)
{
    __shared__ float ks[512 * 20];   // [m][d] pad 20
    __shared__ float vs[512 * 20];
    const int grp = blockIdx.x;
    const int qc = grp & 3, hd = (grp >> 2) & 3, b = grp >> 4;
    const int n  = (blockIdx.y << 8) + threadIdx.x;
    const float* base = qkv + ((size_t)(b * 192 + hd * 48) * 4) * N_PIX;

    float q[16];
#pragma unroll
    for (int d = 0; d < 16; d++)
        q[d] = base[((size_t)d * 4 + qc) * N_PIX + n] * 0.25f;

    float M = -1e30f, L = 0.f;
    float acc[16];
#pragma unroll
    for (int d = 0; d < 16; d++) acc[d] = 0.f;

    for (int t = 0; t < 2; t++) {
        const int m0 = t << 9;
        __syncthreads();
#pragma unroll
        for (int i = 0; i < 32; i++) {
            int flat = i * 256 + threadIdx.x;
            int d = flat >> 9, m = flat & 511;
            ks[m * 20 + d] = base[((size_t)(16 + d) * 4 + qc) * N_PIX + m0 + m];
            vs[m * 20 + d] = base[((size_t)(32 + d) * 4 + qc) * N_PIX + m0 + m];
        }
        __syncthreads();

        for (int g = 0; g < 64; g++) {
            const float* kb = &ks[g * 160];
            float s[8];
#pragma unroll
            for (int i = 0; i < 8; i++) {
                const float* kp = kb + i * 20;
                float acc0 = q[0] * kp[0], acc1 = q[1] * kp[1];
                float acc2 = q[2] * kp[2], acc3 = q[3] * kp[3];
#pragma unroll
                for (int d = 4; d < 16; d += 4) {
                    acc0 += q[d]     * kp[d];
                    acc1 += q[d + 1] * kp[d + 1];
                    acc2 += q[d + 2] * kp[d + 2];
                    acc3 += q[d + 3] * kp[d + 3];
                }
                s[i] = (acc0 + acc1) + (acc2 + acc3);
            }
            float t0 = fmaxf(s[0], s[1]), t1 = fmaxf(s[2], s[3]);
            float t2 = fmaxf(s[4], s[5]), t3 = fmaxf(s[6], s[7]);
            float tm = fmaxf(fmaxf(t0, t1), fmaxf(t2, t3));
            float nM = fmaxf(M, tm);
            float r  = __expf(M - nM);
            M = nM;
            L *= r;
#pragma unroll
            for (int d = 0; d < 16; d++) acc[d] *= r;
            float e[8];
#pragma unroll
            for (int i = 0; i < 8; i++) e[i] = __expf(s[i] - nM);
#pragma unroll
            for (int i = 0; i < 8; i++) L += e[i];
            const float* vb = &vs[g * 160];
#pragma unroll
            for (int i = 0; i < 8; i++) {
                const float* vp = vb + i * 20;
#pragma unroll
                for (int d = 0; d < 16; d++) acc[d] += e[i] * vp[d];
            }
        }
    }
    float inv = 1.f / L;
    float* ob = o + ((size_t)(b * 64 + hd * 16) * 4 + qc) * N_PIX + n;
#pragma unroll
    for (int d = 0; d < 16; d++) ob[(size_t)d * 4096] = acc[d] * inv;
}

// ---------------------------------------------------------------------------
// 3x3 grouped quaternion conv + residual add.
// ---------------------------------------------------------------------------
__global__ __launch_bounds__(256) void pe_conv_kernel(
    const float* __restrict__ x,
    const float* __restrict__ w,
    const float* __restrict__ bias,
    float* __restrict__ y)
{
    const int bid = blockIdx.x;
    const int pt = bid & 3, co = (bid >> 2) & 63, b = bid >> 8;
    const int p = (pt << 8) + threadIdx.x;
    const int hh = p >> 5, ww = p & 31;
    const int g4 = (co >> 2) << 2;

    float a0 = bias[co * 4 + 0], a1 = bias[co * 4 + 1];
    float a2 = bias[co * 4 + 2], a3 = bias[co * 4 + 3];
    const float* xb = x + (size_t)b * 64 * 4096;
    const float* wb = w + co * 36;

#pragma unroll
    for (int dy = 0; dy < 3; dy++) {
        int yy = hh + dy - 1;
        if ((unsigned)yy >= 32u) continue;
#pragma unroll
        for (int dx = 0; dx < 3; dx++) {
            int xx = ww + dx - 1;
            if ((unsigned)xx >= 32u) continue;
            int sp = yy * 32 + xx;
#pragma unroll
            for (int cl = 0; cl < 4; cl++) {
                const float* xp = xb + (size_t)(g4 + cl) * 4096 + sp;
                float xr = xp[0], xi = xp[1024], xj = xp[2048], xk = xp[3072];
                const float* wp = wb + cl * 9 + dy * 3 + dx;
                float wr = wp[0], wi = wp[2304], wj2 = wp[4608], wk = wp[6912];
                a0 += xr * wr - xi * wi  - xj * wj2 - xk * wk;
                a1 += xr * wi + xi * wr  + xj * wk  - xk * wj2;
                a2 += xr * wj2 - xi * wk + xj * wr  + xk * wi;
                a3 += xr * wk + xi * wj2 - xj * wi  + xk * wr;
            }
        }
    }
    size_t ob = (size_t)b * 64 * 4096 + (size_t)co * 4096 + p;
    y[ob]        = x[ob]        + a0;
    y[ob + 1024] = x[ob + 1024] + a1;
    y[ob + 2048] = x[ob + 2048] + a2;
    y[ob + 3072] = x[ob + 3072] + a3;
}

// ---------------------------------------------------------------------------
extern "C" void kernel_launch(void* const* d_in, const int* in_sizes, int n_in,
                              void* d_out, int out_size, void* d_ws, size_t ws_size,
                              hipStream_t stream)
{
    const float* x      = (const float*)d_in[0];
    const float* cv1_w  = (const float*)d_in[1];
    const float* bn1_g  = (const float*)d_in[2];
    const float* bn1_b  = (const float*)d_in[3];
    const float* qkv_w  = (const float*)d_in[4];
    const float* qkv_b  = (const float*)d_in[5];
    const float* proj_w = (const float*)d_in[6];
    const float* proj_b = (const float*)d_in[7];
    const float* pe_w   = (const float*)d_in[8];
    const float* pe_b   = (const float*)d_in[9];
    const float* ang    = (const float*)d_in[10];
    const float* anb    = (const float*)d_in[11];
    const float* ffn1_w = (const float*)d_in[12];
    const float* fbn1_g = (const float*)d_in[13];
    const float* fbn1_b = (const float*)d_in[14];
    const float* ffn2_w = (const float*)d_in[15];
    const float* fbn2_g = (const float*)d_in[16];
    const float* fbn2_b = (const float*)d_in[17];
    const float* cv2_w  = (const float*)d_in[18];
    const float* bn2_g  = (const float*)d_in[19];
    const float* bn2_b  = (const float*)d_in[20];
    float* out = (float*)d_out;

    float* ws    = (float*)d_ws;
    float* hbuf  = ws;                                  // [4,128,4,1024]
    float* qkvb  = ws + 2097152;                        // [4,192,4,1024]
    float* bufA  = ws + 2097152 + 3145728;              // [4,64,4,1024]
    float* bufD  = bufA + 1048576;                      // [4,128,4,1024]
    float* stats = bufD + 2097152;                      // 1024 floats
    float* wtb   = stats + 1024;                        // 262144 floats
    float* wt_cv1  = wtb;                               // 65536
    float* wt_qkv  = wtb + 65536;                       // 49152
    float* wt_proj = wtb + 65536 + 49152;               // 16384
    float* wt_ffn1 = wt_proj + 16384;                   // 32768
    float* wt_ffn2 = wt_ffn1 + 32768;                   // 32768
    float* wt_cv2  = wt_ffn2 + 32768;                   // 65536
    float* bufB  = qkvb;                                // alias
    float* bufC  = qkvb + 1048576;                      // alias
    float* cv2o  = qkvb;                                // alias

    const int S128 = 128 * 4096, S192 = 192 * 4096, S64 = 64 * 4096;

    // 0. weight transposes
    wprep_kernel<<<64, 256, 0, stream>>>(cv1_w,  wt_cv1,  128, 128);
    wprep_kernel<<<48, 256, 0, stream>>>(qkv_w,  wt_qkv,  192, 64);
    wprep_kernel<<<16, 256, 0, stream>>>(proj_w, wt_proj, 64,  64);
    wprep_kernel<<<32, 256, 0, stream>>>(ffn1_w, wt_ffn1, 128, 64);
    wprep_kernel<<<32, 256, 0, stream>>>(ffn2_w, wt_ffn2, 64,  128);
    wprep_kernel<<<64, 256, 0, stream>>>(cv2_w,  wt_cv2,  128, 128);

    // 1. cv1 + iqbn + relu -> hbuf
    qconv1x1_kernel<<<dim3(128, 4), 256, 0, stream>>>(x, S128, wt_cv1, nullptr, hbuf, S128, 128, 128);
    iqbn_stats_kernel<<<512, 256, 0, stream>>>(hbuf, S128, stats);
    iqbn_apply_kernel<<<2048, 256, 0, stream>>>(hbuf, S128, hbuf, S128, stats, bn1_g, bn1_b, 512, 1);

    // 2. qkv conv (a = hbuf[:, :64]) -> qkvb
    qconv1x1_kernel<<<dim3(128, 6), 256, 0, stream>>>(hbuf, S128, wt_qkv, qkv_b, qkvb, S192, 64, 192);

    // 3. attention -> bufA
    qattn_kernel<<<dim3(64, 4), 256, 0, stream>>>(qkvb, bufA);

    // 4. pe conv + residual -> bufB
    pe_conv_kernel<<<1024, 256, 0, stream>>>(bufA, pe_w, pe_b, bufB);

    // 5. proj conv -> bufC ; iqbn
    qconv1x1_kernel<<<dim3(128, 2), 256, 0, stream>>>(bufB, S64, wt_proj, proj_b, bufC, S64, 64, 64);
    iqbn_stats_kernel<<<256, 256, 0, stream>>>(bufC, S64, stats);
    iqbn_apply_kernel<<<1024, 256, 0, stream>>>(bufC, S64, bufC, S64, stats, ang, anb, 256, 0);

    // 6. ffn1 -> bufD ; iqbn + relu
    qconv1x1_kernel<<<dim3(128, 4), 256, 0, stream>>>(bufC, S64, wt_ffn1, nullptr, bufD, S128, 64, 128);
    iqbn_stats_kernel<<<512, 256, 0, stream>>>(bufD, S128, stats);
    iqbn_apply_kernel<<<2048, 256, 0, stream>>>(bufD, S128, bufD, S128, stats, fbn1_g, fbn1_b, 512, 1);

    // 7. ffn2 -> bufA ; iqbn -> hbuf[:, :64]
    qconv1x1_kernel<<<dim3(128, 2), 256, 0, stream>>>(bufD, S128, wt_ffn2, nullptr, bufA, S64, 128, 64);
    iqbn_stats_kernel<<<256, 256, 0, stream>>>(bufA, S64, stats);
    iqbn_apply_kernel<<<1024, 256, 0, stream>>>(bufA, S64, hbuf, S128, stats, fbn2_g, fbn2_b, 256, 0);

    // 8. cv2 -> cv2o ; iqbn + relu -> out
    qconv1x1_kernel<<<dim3(128, 4), 256, 0, stream>>>(hbuf, S128, wt_cv2, nullptr, cv2o, S128, 128, 128);
    iqbn_stats_kernel<<<512, 256, 0, stream>>>(cv2o, S128, stats);
    iqbn_apply_kernel<<<2048, 256, 0, stream>>>(cv2o, S128, out, S128, stats, bn2_g, bn2_b, 512, 1);
}

// Round 3
// 408.755 us; speedup vs baseline: 1.7044x; 1.4870x over previous
//
#include <hip/hip_runtime.h>

#define N_PIX 1024

typedef __attribute__((ext_vector_type(8))) short bf16x8;
typedef __attribute__((ext_vector_type(4))) float f32x4;

__device__ inline ushort f2bf(float f) {
    union { float f; unsigned u; } v; v.f = f;
    unsigned u = v.u;
    return (ushort)((u + 0x7FFF + ((u >> 16) & 1)) >> 16);
}

// ---------------------------------------------------------------------------
// Expand quaternion weight w[4][Cout][Cin] -> Hamilton matrix Wx[4Cout][4Cin] bf16
// Y[(co,c)] = sum_(ci,c') Wx[(co,c)][(ci,c')] X[(ci,c')]
// ---------------------------------------------------------------------------
__global__ __launch_bounds__(256) void wexpand_kernel(
    const float* __restrict__ w, ushort* __restrict__ wx, int Cout, int Cin)
{
    int idx = blockIdx.x * 256 + threadIdx.x;
    int K = 4 * Cin;
    if (idx >= 4 * Cout * K) return;
    int m = idx / K, k = idx - m * K;
    int co = m >> 2, c = m & 3, ci = k >> 2, cp = k & 3;
    // comp/sign tables for Hamilton product
    const int   CT[4][4] = {{0,1,2,3},{1,0,3,2},{2,3,0,1},{3,2,1,0}};
    const float ST[4][4] = {{1.f,-1.f,-1.f,-1.f},{1.f,1.f,1.f,-1.f},
                            {1.f,-1.f,1.f,1.f},{1.f,1.f,-1.f,1.f}};
    float val = ST[c][cp] * w[(size_t)CT[c][cp] * Cout * Cin + (size_t)co * Cin + ci];
    wx[idx] = f2bf(val);
}

// ---------------------------------------------------------------------------
// Pack fp32 activations [b][K][1024] (channel-major) -> bf16 [4096][K] (pixel-major)
// grid (K/32, 16), block 256. LDS transpose 32k x 256p.
// ---------------------------------------------------------------------------
__global__ __launch_bounds__(256) void pack_kernel(
    const float* __restrict__ src, int sbs, ushort* __restrict__ xp, int K)
{
    __shared__ float t[32][257];
    const int k0 = blockIdx.x * 32;
    const int P0 = blockIdx.y * 256;
    const int b = P0 >> 10, p0 = P0 & 1023;
    const float* s = src + (size_t)b * sbs + (size_t)k0 * N_PIX + p0;
#pragma unroll
    for (int i = 0; i < 32; i++)
        t[i][threadIdx.x] = s[i * N_PIX + threadIdx.x];
    __syncthreads();
#pragma unroll
    for (int j = 0; j < 32; j++) {
        int flat = j * 256 + threadIdx.x;
        int kk = flat & 31, p = flat >> 5;
        xp[(size_t)(P0 + p) * K + k0 + kk] = f2bf(t[kk][p]);
    }
}

// ---------------------------------------------------------------------------
// bf16 MFMA GEMM: D[M][4096] = Wx[M][K] * Xp^T  (Xp is [4096][K])
// Output to fp32 y[b][M][1024] (+optional bias[M]).
// grid (M/64, 32), block 256 (4 waves as 2x2, each 32m x 64n).
// LDS frag layout [kb][row][8k] so every access is b128.
// ---------------------------------------------------------------------------
__global__ __launch_bounds__(256) void qgemm_kernel(
    const ushort* __restrict__ xp,
    const ushort* __restrict__ wx,
    const float* __restrict__ bias,
    float* __restrict__ y, int ybs,
    int M, int K)
{
    __shared__ ushort As[64 * 32];    // ((kb*64)+m)*8+j
    __shared__ ushort Bs[128 * 32];   // ((kb*128)+n)*8+j
    const int tid = threadIdx.x;
    const int m0 = blockIdx.x * 64;
    const int P0 = blockIdx.y * 128;
    const int b  = P0 >> 10;
    const int p0 = P0 & 1023;
    const int w  = tid >> 6;
    const int l  = tid & 63;
    const int wm = w >> 1, wn = w & 1;

    const f32x4 z = {0.f, 0.f, 0.f, 0.f};
    f32x4 acc[2][4];
#pragma unroll
    for (int mi = 0; mi < 2; mi++)
#pragma unroll
        for (int ni = 0; ni < 4; ni++) acc[mi][ni] = z;

    const int am  = tid >> 2, akb = tid & 3;   // A staging: 64m x 4kb
    const int lkb = l >> 4,   lr  = l & 15;    // fragment lane decode

    for (int k0 = 0; k0 < K; k0 += 32) {
        __syncthreads();
        // stage A (64x32) : one b128 per thread
        *(int4*)&As[((akb * 64) + am) * 8] =
            *(const int4*)&wx[(size_t)(m0 + am) * K + k0 + akb * 8];
        // stage B (128x32): two b128 per thread
#pragma unroll
        for (int it = 0; it < 2; it++) {
            int n = it * 64 + (tid >> 2);
            *(int4*)&Bs[((akb * 128) + n) * 8] =
                *(const int4*)&xp[(size_t)(P0 + n) * K + k0 + akb * 8];
        }
        __syncthreads();

        bf16x8 af[2], bf[4];
#pragma unroll
        for (int mi = 0; mi < 2; mi++)
            af[mi] = *(const bf16x8*)&As[((lkb * 64) + wm * 32 + mi * 16 + lr) * 8];
#pragma unroll
        for (int ni = 0; ni < 4; ni++)
            bf[ni] = *(const bf16x8*)&Bs[((lkb * 128) + wn * 64 + ni * 16 + lr) * 8];
#pragma unroll
        for (int mi = 0; mi < 2; mi++)
#pragma unroll
            for (int ni = 0; ni < 4; ni++)
                acc[mi][ni] = __builtin_amdgcn_mfma_f32_16x16x32_bf16(
                    af[mi], bf[ni], acc[mi][ni], 0, 0, 0);
    }

    // epilogue: D col = lane&15, row = (lane>>4)*4 + r   [m89-verified]
    float* yb = y + (size_t)b * ybs;
#pragma unroll
    for (int mi = 0; mi < 2; mi++) {
        int mrow = m0 + wm * 32 + mi * 16 + lkb * 4;
#pragma unroll
        for (int ni = 0; ni < 4; ni++) {
            int col = p0 + wn * 64 + ni * 16 + lr;
#pragma unroll
            for (int r = 0; r < 4; r++) {
                float v = acc[mi][ni][r];
                if (bias) v += bias[mrow + r];
                yb[(size_t)(mrow + r) * N_PIX + col] = v;
            }
        }
    }
}

// ---------------------------------------------------------------------------
// IQBN stats: one block per (c,qc).
// ---------------------------------------------------------------------------
__global__ __launch_bounds__(256) void iqbn_stats_kernel(
    const float* __restrict__ x, int xbs, float* __restrict__ stats)
{
    const int cq = blockIdx.x;
    float s = 0.f, s2 = 0.f;
#pragma unroll
    for (int b = 0; b < 4; b++) {
        const float* xp = x + (size_t)b * xbs + (size_t)cq * N_PIX;
        for (int p = threadIdx.x; p < N_PIX; p += 256) {
            float v = xp[p];
            s += v; s2 += v * v;
        }
    }
#pragma unroll
    for (int o = 32; o > 0; o >>= 1) {
        s  += __shfl_down(s, o);
        s2 += __shfl_down(s2, o);
    }
    __shared__ float red[8];
    int wid = threadIdx.x >> 6, lane = threadIdx.x & 63;
    if (lane == 0) { red[wid * 2] = s; red[wid * 2 + 1] = s2; }
    __syncthreads();
    if (threadIdx.x == 0) {
        s = 0.f; s2 = 0.f;
#pragma unroll
        for (int i = 0; i < 4; i++) { s += red[2 * i]; s2 += red[2 * i + 1]; }
        const float inv = 1.0f / 4096.0f;
        float mean = s * inv;
        float var  = s2 * inv - mean * mean;
        stats[cq * 2]     = mean;
        stats[cq * 2 + 1] = rsqrtf(var + 1e-5f);
    }
}

// ---------------------------------------------------------------------------
// IQBN apply (+optional relu).
// ---------------------------------------------------------------------------
__global__ __launch_bounds__(256) void iqbn_apply_kernel(
    const float* __restrict__ x, int xbs,
    float* __restrict__ y, int ybs,
    const float* __restrict__ stats,
    const float* __restrict__ g, const float* __restrict__ bta,
    int C4, int relu)
{
    int cq = blockIdx.x % C4;
    int b  = blockIdx.x / C4;
    float mean = stats[cq * 2], rstd = stats[cq * 2 + 1];
    float ga = g[cq] * rstd;
    float bb = bta[cq] - mean * ga;
    const float4* xp = (const float4*)(x + (size_t)b * xbs + (size_t)cq * N_PIX);
    float4*       yp = (float4*)(y + (size_t)b * ybs + (size_t)cq * N_PIX);
    float4 v = xp[threadIdx.x];
    v.x = v.x * ga + bb; v.y = v.y * ga + bb; v.z = v.z * ga + bb; v.w = v.w * ga + bb;
    if (relu) {
        v.x = fmaxf(v.x, 0.f); v.y = fmaxf(v.y, 0.f);
        v.z = fmaxf(v.z, 0.f); v.w = fmaxf(v.w, 0.f);
    }
    yp[threadIdx.x] = v;
}

// ---------------------------------------------------------------------------
// Attention (v1 structure, known-good): per-m online softmax.
// qkv: [B,192,4,1024]; o: [B,64,4,1024]; grid (64,4), block 256.
// ---------------------------------------------------------------------------
__global__ __launch_bounds__(256) void qattn_kernel(
    const float* __restrict__ qkv, float* __restrict__ o)
{
    __shared__ float ks[512 * 20];
    __shared__ float vs[512 * 20];
    const int grp = blockIdx.x;
    const int qc = grp & 3, hd = (grp >> 2) & 3, b = grp >> 4;
    const int n  = (blockIdx.y << 8) + threadIdx.x;
    const float* base = qkv + ((size_t)(b * 192 + hd * 48) * 4) * N_PIX;

    float q[16];
#pragma unroll
    for (int d = 0; d < 16; d++)
        q[d] = base[((size_t)d * 4 + qc) * N_PIX + n] * 0.25f;

    float M = -1e30f, L = 0.f;
    float acc[16];
#pragma unroll
    for (int d = 0; d < 16; d++) acc[d] = 0.f;

    for (int t = 0; t < 2; t++) {
        const int m0 = t << 9;
        __syncthreads();
#pragma unroll
        for (int i = 0; i < 32; i++) {
            int flat = i * 256 + threadIdx.x;
            int d = flat >> 9, m = flat & 511;
            ks[m * 20 + d] = base[((size_t)(16 + d) * 4 + qc) * N_PIX + m0 + m];
            vs[m * 20 + d] = base[((size_t)(32 + d) * 4 + qc) * N_PIX + m0 + m];
        }
        __syncthreads();

        for (int m = 0; m < 512; m++) {
            const float* kp = &ks[m * 20];
            float s = 0.f;
#pragma unroll
            for (int d = 0; d < 16; d++) s += q[d] * kp[d];
            float nM = fmaxf(M, s);
            float r  = __expf(M - nM);
            float e  = __expf(s - nM);
            L = L * r + e;
            M = nM;
            const float* vp = &vs[m * 20];
#pragma unroll
            for (int d = 0; d < 16; d++) acc[d] = acc[d] * r + e * vp[d];
        }
    }
    float inv = 1.f / L;
    float* ob = o + ((size_t)(b * 64 + hd * 16) * 4 + qc) * N_PIX + n;
#pragma unroll
    for (int d = 0; d < 16; d++) ob[(size_t)d * 4096] = acc[d] * inv;
}

// ---------------------------------------------------------------------------
// 3x3 grouped quaternion conv + residual add.
// ---------------------------------------------------------------------------
__global__ __launch_bounds__(256) void pe_conv_kernel(
    const float* __restrict__ x,
    const float* __restrict__ w,
    const float* __restrict__ bias,
    float* __restrict__ y)
{
    const int bid = blockIdx.x;
    const int pt = bid & 3, co = (bid >> 2) & 63, b = bid >> 8;
    const int p = (pt << 8) + threadIdx.x;
    const int hh = p >> 5, ww = p & 31;
    const int g4 = (co >> 2) << 2;

    float a0 = bias[co * 4 + 0], a1 = bias[co * 4 + 1];
    float a2 = bias[co * 4 + 2], a3 = bias[co * 4 + 3];
    const float* xb = x + (size_t)b * 64 * 4096;
    const float* wb = w + co * 36;

#pragma unroll
    for (int dy = 0; dy < 3; dy++) {
        int yy = hh + dy - 1;
        if ((unsigned)yy >= 32u) continue;
#pragma unroll
        for (int dx = 0; dx < 3; dx++) {
            int xx = ww + dx - 1;
            if ((unsigned)xx >= 32u) continue;
            int sp = yy * 32 + xx;
#pragma unroll
            for (int cl = 0; cl < 4; cl++) {
                const float* xp = xb + (size_t)(g4 + cl) * 4096 + sp;
                float xr = xp[0], xi = xp[1024], xj = xp[2048], xk = xp[3072];
                const float* wp = wb + cl * 9 + dy * 3 + dx;
                float wr = wp[0], wi = wp[2304], wj2 = wp[4608], wk = wp[6912];
                a0 += xr * wr - xi * wi  - xj * wj2 - xk * wk;
                a1 += xr * wi + xi * wr  + xj * wk  - xk * wj2;
                a2 += xr * wj2 - xi * wk + xj * wr  + xk * wi;
                a3 += xr * wk + xi * wj2 - xj * wi  + xk * wr;
            }
        }
    }
    size_t ob = (size_t)b * 64 * 4096 + (size_t)co * 4096 + p;
    y[ob]        = x[ob]        + a0;
    y[ob + 1024] = x[ob + 1024] + a1;
    y[ob + 2048] = x[ob + 2048] + a2;
    y[ob + 3072] = x[ob + 3072] + a3;
}

// ---------------------------------------------------------------------------
extern "C" void kernel_launch(void* const* d_in, const int* in_sizes, int n_in,
                              void* d_out, int out_size, void* d_ws, size_t ws_size,
                              hipStream_t stream)
{
    const float* x      = (const float*)d_in[0];
    const float* cv1_w  = (const float*)d_in[1];
    const float* bn1_g  = (const float*)d_in[2];
    const float* bn1_b  = (const float*)d_in[3];
    const float* qkv_w  = (const float*)d_in[4];
    const float* qkv_b  = (const float*)d_in[5];
    const float* proj_w = (const float*)d_in[6];
    const float* proj_b = (const float*)d_in[7];
    const float* pe_w   = (const float*)d_in[8];
    const float* pe_b   = (const float*)d_in[9];
    const float* ang    = (const float*)d_in[10];
    const float* anb    = (const float*)d_in[11];
    const float* ffn1_w = (const float*)d_in[12];
    const float* fbn1_g = (const float*)d_in[13];
    const float* fbn1_b = (const float*)d_in[14];
    const float* ffn2_w = (const float*)d_in[15];
    const float* fbn2_g = (const float*)d_in[16];
    const float* fbn2_b = (const float*)d_in[17];
    const float* cv2_w  = (const float*)d_in[18];
    const float* bn2_g  = (const float*)d_in[19];
    const float* bn2_b  = (const float*)d_in[20];
    float* out = (float*)d_out;

    float* ws    = (float*)d_ws;
    float* hbuf  = ws;                       // [4,128,4,1024]
    float* qkvb  = ws + 2097152;             // [4,192,4,1024]
    float* bufA  = ws + 5242880;             // [4,64,4,1024]
    float* bufD  = ws + 6291456;             // [4,128,4,1024]
    float* stats = ws + 8388608;             // 1024
    ushort* Xp   = (ushort*)(ws + 8389632);  // up to 4096x512 bf16
    ushort* Wx   = (ushort*)(ws + 9438208);  // up to 512x512 bf16
    float* bufB  = qkvb;                     // alias (qkv dead after attn)
    float* bufC  = qkvb + 1048576;           // alias
    float* cv2o  = qkvb;                     // alias

    const int S128 = 128 * 4096, S192 = 192 * 4096, S64 = 64 * 4096;

    // 1. cv1 (512x4096x512) + iqbn + relu -> hbuf
    wexpand_kernel<<<1024, 256, 0, stream>>>(cv1_w, Wx, 128, 128);
    pack_kernel<<<dim3(16, 16), 256, 0, stream>>>(x, S128, Xp, 512);
    qgemm_kernel<<<dim3(8, 32), 256, 0, stream>>>(Xp, Wx, nullptr, hbuf, S128, 512, 512);
    iqbn_stats_kernel<<<512, 256, 0, stream>>>(hbuf, S128, stats);
    iqbn_apply_kernel<<<2048, 256, 0, stream>>>(hbuf, S128, hbuf, S128, stats, bn1_g, bn1_b, 512, 1);

    // 2. qkv (768x4096x256, a-half input) -> qkvb
    wexpand_kernel<<<768, 256, 0, stream>>>(qkv_w, Wx, 192, 64);
    pack_kernel<<<dim3(8, 16), 256, 0, stream>>>(hbuf, S128, Xp, 256);
    qgemm_kernel<<<dim3(12, 32), 256, 0, stream>>>(Xp, Wx, qkv_b, qkvb, S192, 768, 256);

    // 3. attention -> bufA
    qattn_kernel<<<dim3(64, 4), 256, 0, stream>>>(qkvb, bufA);

    // 4. pe conv + residual -> bufB
    pe_conv_kernel<<<1024, 256, 0, stream>>>(bufA, pe_w, pe_b, bufB);

    // 5. proj (256x4096x256) -> bufC ; iqbn
    wexpand_kernel<<<256, 256, 0, stream>>>(proj_w, Wx, 64, 64);
    pack_kernel<<<dim3(8, 16), 256, 0, stream>>>(bufB, S64, Xp, 256);
    qgemm_kernel<<<dim3(4, 32), 256, 0, stream>>>(Xp, Wx, proj_b, bufC, S64, 256, 256);
    iqbn_stats_kernel<<<256, 256, 0, stream>>>(bufC, S64, stats);
    iqbn_apply_kernel<<<1024, 256, 0, stream>>>(bufC, S64, bufC, S64, stats, ang, anb, 256, 0);

    // 6. ffn1 (512x4096x256) -> bufD ; iqbn + relu
    wexpand_kernel<<<512, 256, 0, stream>>>(ffn1_w, Wx, 128, 64);
    pack_kernel<<<dim3(8, 16), 256, 0, stream>>>(bufC, S64, Xp, 256);
    qgemm_kernel<<<dim3(8, 32), 256, 0, stream>>>(Xp, Wx, nullptr, bufD, S128, 512, 256);
    iqbn_stats_kernel<<<512, 256, 0, stream>>>(bufD, S128, stats);
    iqbn_apply_kernel<<<2048, 256, 0, stream>>>(bufD, S128, bufD, S128, stats, fbn1_g, fbn1_b, 512, 1);

    // 7. ffn2 (256x4096x512) -> bufA ; iqbn -> hbuf[:, :64] (free concat)
    wexpand_kernel<<<512, 256, 0, stream>>>(ffn2_w, Wx, 64, 128);
    pack_kernel<<<dim3(16, 16), 256, 0, stream>>>(bufD, S128, Xp, 512);
    qgemm_kernel<<<dim3(4, 32), 256, 0, stream>>>(Xp, Wx, nullptr, bufA, S64, 256, 512);
    iqbn_stats_kernel<<<256, 256, 0, stream>>>(bufA, S64, stats);
    iqbn_apply_kernel<<<1024, 256, 0, stream>>>(bufA, S64, hbuf, S128, stats, fbn2_g, fbn2_b, 256, 0);

    // 8. cv2 (512x4096x512) -> cv2o ; iqbn + relu -> out
    wexpand_kernel<<<1024, 256, 0, stream>>>(cv2_w, Wx, 128, 128);
    pack_kernel<<<dim3(16, 16), 256, 0, stream>>>(hbuf, S128, Xp, 512);
    qgemm_kernel<<<dim3(8, 32), 256, 0, stream>>>(Xp, Wx, nullptr, cv2o, S128, 512, 512);
    iqbn_stats_kernel<<<512, 256, 0, stream>>>(cv2o, S128, stats);
    iqbn_apply_kernel<<<2048, 256, 0, stream>>>(cv2o, S128, out, S128, stats, bn2_g, bn2_b, 512, 1);
}

// Round 5
// 307.233 us; speedup vs baseline: 2.2677x; 1.3304x over previous
//
#include <hip/hip_runtime.h>

#define N_PIX 1024

typedef __attribute__((ext_vector_type(8))) short bf16x8;
typedef __attribute__((ext_vector_type(4))) float f32x4;

__device__ inline ushort f2bf(float f) {
    union { float f; unsigned u; } v; v.f = f;
    unsigned u = v.u;
    return (ushort)((u + 0x7FFF + ((u >> 16) & 1)) >> 16);
}
__device__ inline float bf2f(ushort h) {
    union { unsigned u; float f; } v; v.u = ((unsigned)h) << 16; return v.f;
}

// ---------------------------------------------------------------------------
// Expand quaternion weight w[4][Cout][Cin] -> Hamilton matrix Wx[4Cout][4Cin] bf16
// ---------------------------------------------------------------------------
__global__ __launch_bounds__(256) void wexpand_kernel(
    const float* __restrict__ w, ushort* __restrict__ wx, int Cout, int Cin)
{
    int idx = blockIdx.x * 256 + threadIdx.x;
    int K = 4 * Cin;
    if (idx >= 4 * Cout * K) return;
    int m = idx / K, k = idx - m * K;
    int co = m >> 2, c = m & 3, ci = k >> 2, cp = k & 3;
    const int   CT[4][4] = {{0,1,2,3},{1,0,3,2},{2,3,0,1},{3,2,1,0}};
    const float ST[4][4] = {{1.f,-1.f,-1.f,-1.f},{1.f,1.f,1.f,-1.f},
                            {1.f,-1.f,1.f,1.f},{1.f,1.f,-1.f,1.f}};
    float val = ST[c][cp] * w[(size_t)CT[c][cp] * Cout * Cin + (size_t)co * Cin + ci];
    wx[idx] = f2bf(val);
}

// ---------------------------------------------------------------------------
// Pack fp32 activations [b][K][1024] -> bf16 [4096][K] (pixel-major)
// ---------------------------------------------------------------------------
__global__ __launch_bounds__(256) void pack_kernel(
    const float* __restrict__ src, int sbs, ushort* __restrict__ xp, int K)
{
    __shared__ float t[32][257];
    const int k0 = blockIdx.x * 32;
    const int P0 = blockIdx.y * 256;
    const int b = P0 >> 10, p0 = P0 & 1023;
    const float* s = src + (size_t)b * sbs + (size_t)k0 * N_PIX + p0;
#pragma unroll
    for (int i = 0; i < 32; i++)
        t[i][threadIdx.x] = s[i * N_PIX + threadIdx.x];
    __syncthreads();
#pragma unroll
    for (int j = 0; j < 32; j++) {
        int flat = j * 256 + threadIdx.x;
        int kk = flat & 31, p = flat >> 5;
        xp[(size_t)(P0 + p) * K + k0 + kk] = f2bf(t[kk][p]);
    }
}

// ---------------------------------------------------------------------------
// bf16 MFMA GEMM: D[M][4096] = Wx[M][K] * Xp^T
// ---------------------------------------------------------------------------
__global__ __launch_bounds__(256) void qgemm_kernel(
    const ushort* __restrict__ xp,
    const ushort* __restrict__ wx,
    const float* __restrict__ bias,
    float* __restrict__ y, int ybs,
    int M, int K)
{
    __shared__ ushort As[64 * 32];
    __shared__ ushort Bs[128 * 32];
    const int tid = threadIdx.x;
    const int m0 = blockIdx.x * 64;
    const int P0 = blockIdx.y * 128;
    const int b  = P0 >> 10;
    const int p0 = P0 & 1023;
    const int w  = tid >> 6;
    const int l  = tid & 63;
    const int wm = w >> 1, wn = w & 1;

    const f32x4 z = {0.f, 0.f, 0.f, 0.f};
    f32x4 acc[2][4];
#pragma unroll
    for (int mi = 0; mi < 2; mi++)
#pragma unroll
        for (int ni = 0; ni < 4; ni++) acc[mi][ni] = z;

    const int am  = tid >> 2, akb = tid & 3;
    const int lkb = l >> 4,   lr  = l & 15;

    for (int k0 = 0; k0 < K; k0 += 32) {
        __syncthreads();
        *(int4*)&As[((akb * 64) + am) * 8] =
            *(const int4*)&wx[(size_t)(m0 + am) * K + k0 + akb * 8];
#pragma unroll
        for (int it = 0; it < 2; it++) {
            int n = it * 64 + (tid >> 2);
            *(int4*)&Bs[((akb * 128) + n) * 8] =
                *(const int4*)&xp[(size_t)(P0 + n) * K + k0 + akb * 8];
        }
        __syncthreads();

        bf16x8 af[2], bf[4];
#pragma unroll
        for (int mi = 0; mi < 2; mi++)
            af[mi] = *(const bf16x8*)&As[((lkb * 64) + wm * 32 + mi * 16 + lr) * 8];
#pragma unroll
        for (int ni = 0; ni < 4; ni++)
            bf[ni] = *(const bf16x8*)&Bs[((lkb * 128) + wn * 64 + ni * 16 + lr) * 8];
#pragma unroll
        for (int mi = 0; mi < 2; mi++)
#pragma unroll
            for (int ni = 0; ni < 4; ni++)
                acc[mi][ni] = __builtin_amdgcn_mfma_f32_16x16x32_bf16(
                    af[mi], bf[ni], acc[mi][ni], 0, 0, 0);
    }

    float* yb = y + (size_t)b * ybs;
#pragma unroll
    for (int mi = 0; mi < 2; mi++) {
        int mrow = m0 + wm * 32 + mi * 16 + lkb * 4;
#pragma unroll
        for (int ni = 0; ni < 4; ni++) {
            int col = p0 + wn * 64 + ni * 16 + lr;
#pragma unroll
            for (int r = 0; r < 4; r++) {
                float v = acc[mi][ni][r];
                if (bias) v += bias[mrow + r];
                yb[(size_t)(mrow + r) * N_PIX + col] = v;
            }
        }
    }
}

// ---------------------------------------------------------------------------
// IQBN stats
// ---------------------------------------------------------------------------
__global__ __launch_bounds__(256) void iqbn_stats_kernel(
    const float* __restrict__ x, int xbs, float* __restrict__ stats)
{
    const int cq = blockIdx.x;
    float s = 0.f, s2 = 0.f;
#pragma unroll
    for (int b = 0; b < 4; b++) {
        const float* xp = x + (size_t)b * xbs + (size_t)cq * N_PIX;
        for (int p = threadIdx.x; p < N_PIX; p += 256) {
            float v = xp[p];
            s += v; s2 += v * v;
        }
    }
#pragma unroll
    for (int o = 32; o > 0; o >>= 1) {
        s  += __shfl_down(s, o);
        s2 += __shfl_down(s2, o);
    }
    __shared__ float red[8];
    int wid = threadIdx.x >> 6, lane = threadIdx.x & 63;
    if (lane == 0) { red[wid * 2] = s; red[wid * 2 + 1] = s2; }
    __syncthreads();
    if (threadIdx.x == 0) {
        s = 0.f; s2 = 0.f;
#pragma unroll
        for (int i = 0; i < 4; i++) { s += red[2 * i]; s2 += red[2 * i + 1]; }
        const float inv = 1.0f / 4096.0f;
        float mean = s * inv;
        float var  = s2 * inv - mean * mean;
        stats[cq * 2]     = mean;
        stats[cq * 2 + 1] = rsqrtf(var + 1e-5f);
    }
}

// ---------------------------------------------------------------------------
// IQBN apply (+optional relu)
// ---------------------------------------------------------------------------
__global__ __launch_bounds__(256) void iqbn_apply_kernel(
    const float* __restrict__ x, int xbs,
    float* __restrict__ y, int ybs,
    const float* __restrict__ stats,
    const float* __restrict__ g, const float* __restrict__ bta,
    int C4, int relu)
{
    int cq = blockIdx.x % C4;
    int b  = blockIdx.x / C4;
    float mean = stats[cq * 2], rstd = stats[cq * 2 + 1];
    float ga = g[cq] * rstd;
    float bb = bta[cq] - mean * ga;
    const float4* xp = (const float4*)(x + (size_t)b * xbs + (size_t)cq * N_PIX);
    float4*       yp = (float4*)(y + (size_t)b * ybs + (size_t)cq * N_PIX);
    float4 v = xp[threadIdx.x];
    v.x = v.x * ga + bb; v.y = v.y * ga + bb; v.z = v.z * ga + bb; v.w = v.w * ga + bb;
    if (relu) {
        v.x = fmaxf(v.x, 0.f); v.y = fmaxf(v.y, 0.f);
        v.z = fmaxf(v.z, 0.f); v.w = fmaxf(v.w, 0.f);
    }
    yp[threadIdx.x] = v;
}

// ---------------------------------------------------------------------------
// MFMA flash attention. One block = one (b,hd,qc) group x 128 n-rows.
// grid (64, 8), block 256 (4 waves; wave owns 32 n).
// hi/lo bf16 split on Q,K,V -> ~fp32-accurate scores.
// sigma-independent score MFMAs (same packing convention on both operands):
//   S = mfma(A1=[kh|kl], B=[qh|ql]) + mfma(A2=[kl|kh], B=[qh|ql])
//     = kh*qh + kl*ql + kl*qh + kh*ql = (kh+kl)*(qh+ql)
// ---------------------------------------------------------------------------
__global__ __launch_bounds__(256) void qattn_kernel(
    const float* __restrict__ qkv, float* __restrict__ o)
{
    __shared__ __attribute__((aligned(16))) char smem[24576];
    // K [64m][32] bf16 (kh 0..31B | kl 32..63B) @0 (4KB); Vh [16d][64m] @4096;
    // Vl @6144; P per-wave [32n][64m] bf16 @8192+w*4096 (epilogue Obuf @8192)
    const int tid = threadIdx.x;
    const int grp = blockIdx.x;
    const int qc = grp & 3, hd = (grp >> 2) & 3, b = grp >> 4;
    const int n0 = blockIdx.y << 7;
    const int w = tid >> 6, lid = tid & 63;
    const int col = lid & 15, g = lid >> 4;
    const int swz = (col & 7) << 4;

    const float* gq = qkv + ((size_t)(b * 192 + hd * 48) * 4 + qc) * N_PIX;

    // Q fragments: B-operand packed [qh(k=0..15) | ql(k=16..31)], scale folded
    bf16x8 qf[2];
#pragma unroll
    for (int ns = 0; ns < 2; ns++) {
        int n = n0 + w * 32 + ns * 16 + col;
        const float* qg = gq + (size_t)((g & 1) * 8) * 4096 + n;
        union { bf16x8 v; ushort u[8]; } qq;
#pragma unroll
        for (int j = 0; j < 8; j++) {
            float qv = qg[(size_t)j * 4096] * 0.25f;
            ushort h = f2bf(qv);
            qq.u[j] = (g >= 2) ? f2bf(qv - bf2f(h)) : h;
        }
        qf[ns] = qq.v;
    }

    const f32x4 z = {0.f, 0.f, 0.f, 0.f};
    f32x4 O[2] = {z, z};
    float M[2] = {-1e30f, -1e30f}, L[2] = {0.f, 0.f};

    const int ml = tid & 63;
    const int d4 = (tid >> 6) << 2;

    for (int t = 0; t < 16; t++) {
        const int m0 = t << 6;
        __syncthreads();
        // ---- stage K (kh|kl halves, full-address XOR swizzle) and V hi/lo ----
        {
            const float* kg = gq + (size_t)(16 + d4) * 4096 + m0 + ml;
            const float* vg = gq + (size_t)(32 + d4) * 4096 + m0 + ml;
            float kv[4], vv[4];
#pragma unroll
            for (int i = 0; i < 4; i++) {
                kv[i] = kg[(size_t)i * 4096];
                vv[i] = vg[(size_t)i * 4096];
            }
            ushort kh[4], kl[4];
#pragma unroll
            for (int i = 0; i < 4; i++) {
                kh[i] = f2bf(kv[i]);
                kl[i] = f2bf(kv[i] - bf2f(kh[i]));
            }
            int sw = (ml & 7) << 4;
            int kbh = (ml * 64 + d4 * 2) ^ sw;
            int kbl = (ml * 64 + 32 + d4 * 2) ^ sw;
            *(uint2*)(smem + kbh) =
                make_uint2((uint)kh[0] | ((uint)kh[1] << 16), (uint)kh[2] | ((uint)kh[3] << 16));
            *(uint2*)(smem + kbl) =
                make_uint2((uint)kl[0] | ((uint)kl[1] << 16), (uint)kl[2] | ((uint)kl[3] << 16));
#pragma unroll
            for (int i = 0; i < 4; i++) {
                int d = d4 + i;
                ushort vh = f2bf(vv[i]);
                ushort vl = f2bf(vv[i] - bf2f(vh));
                int vb = (d * 128 + ml * 2) ^ ((d & 7) << 4);
                *(ushort*)(smem + 4096 + vb) = vh;
                *(ushort*)(smem + 6144 + vb) = vl;
            }
        }
        __syncthreads();

        // ---- S^T = K·Q  (sigma-independent two-MFMA form) ----
        f32x4 s[2][4];
#pragma unroll
        for (int ms = 0; ms < 4; ms++) {
            int rowb = (ms * 16 + col) * 64;
            bf16x8 a1 = *(const bf16x8*)(smem + ((rowb + g * 16) ^ swz));
            bf16x8 a2 = *(const bf16x8*)(smem + ((rowb + ((g ^ 2) * 16)) ^ swz));
#pragma unroll
            for (int ns = 0; ns < 2; ns++) {
                f32x4 c = __builtin_amdgcn_mfma_f32_16x16x32_bf16(a1, qf[ns], z, 0, 0, 0);
                s[ns][ms] = __builtin_amdgcn_mfma_f32_16x16x32_bf16(a2, qf[ns], c, 0, 0, 0);
            }
        }

        // ---- online softmax + P write + O rescale ----
#pragma unroll
        for (int ns = 0; ns < 2; ns++) {
            float tmax = s[ns][0][0];
#pragma unroll
            for (int ms = 0; ms < 4; ms++)
#pragma unroll
                for (int r = 0; r < 4; r++) tmax = fmaxf(tmax, s[ns][ms][r]);
            tmax = fmaxf(tmax, __shfl_xor(tmax, 16));
            tmax = fmaxf(tmax, __shfl_xor(tmax, 32));
            float Mn = fmaxf(M[ns], tmax);
            float rs = __expf(M[ns] - Mn);
            M[ns] = Mn;
            float psum = 0.f;
#pragma unroll
            for (int ms = 0; ms < 4; ms++) {
                f32x4 e;
#pragma unroll
                for (int r = 0; r < 4; r++) {
                    e[r] = __expf(s[ns][ms][r] - Mn);
                    psum += e[r];
                }
                s[ns][ms] = e;
            }
            psum += __shfl_xor(psum, 16);
            psum += __shfl_xor(psum, 32);
            L[ns] = L[ns] * rs + psum;
#pragma unroll
            for (int r = 0; r < 4; r++)
                O[ns][r] *= __shfl(rs, g * 4 + r);
            int nl = ns * 16 + col;
#pragma unroll
            for (int ms = 0; ms < 4; ms++) {
                uint plo = (uint)f2bf(s[ns][ms][0]) | ((uint)f2bf(s[ns][ms][1]) << 16);
                uint phi = (uint)f2bf(s[ns][ms][2]) | ((uint)f2bf(s[ns][ms][3]) << 16);
                int pb = (8192 + w * 4096 + nl * 128 + ms * 32 + g * 8) ^ swz;
                *(uint2*)(smem + pb) = make_uint2(plo, phi);
            }
        }
        __builtin_amdgcn_sched_barrier(0);

        // ---- PV: O^T += P·(vh+vl) ----
#pragma unroll
        for (int s2 = 0; s2 < 2; s2++) {
            int mb = s2 * 64 + g * 16;
            int vb = (col * 128 + mb) ^ swz;
            bf16x8 bvh = *(const bf16x8*)(smem + 4096 + vb);
            bf16x8 bvl = *(const bf16x8*)(smem + 6144 + vb);
#pragma unroll
            for (int ns = 0; ns < 2; ns++) {
                int nl = ns * 16 + col;
                bf16x8 ap = *(const bf16x8*)(smem + ((8192 + w * 4096 + nl * 128 + mb) ^ swz));
                O[ns] = __builtin_amdgcn_mfma_f32_16x16x32_bf16(ap, bvh, O[ns], 0, 0, 0);
                O[ns] = __builtin_amdgcn_mfma_f32_16x16x32_bf16(ap, bvl, O[ns], 0, 0, 0);
            }
        }
    }

    // ---- epilogue: 1/L, transpose via LDS, coalesced store ----
#pragma unroll
    for (int ns = 0; ns < 2; ns++) {
        float invL = 1.f / L[ns];
#pragma unroll
        for (int r = 0; r < 4; r++)
            O[ns][r] *= __shfl(invL, g * 4 + r);
    }
    __syncthreads();
#pragma unroll
    for (int ns = 0; ns < 2; ns++) {
        int nloc = w * 32 + ns * 16 + g * 4;
        int ob = (8192 + col * 512 + nloc * 4) ^ swz;
        *(f32x4*)(smem + ob) = O[ns];
    }
    __syncthreads();
    {
        int d = tid >> 4, nb = (tid & 15) << 3;
        int b0 = (8192 + d * 512 + nb * 4) ^ ((d & 7) << 4);
        int b1 = (8192 + d * 512 + nb * 4 + 16) ^ ((d & 7) << 4);
        float4 o0 = *(const float4*)(smem + b0);
        float4 o1 = *(const float4*)(smem + b1);
        float* op = o + ((size_t)(b * 64 + hd * 16 + d) * 4 + qc) * N_PIX + n0 + nb;
        *(float4*)op = o0;
        *(float4*)(op + 4) = o1;
    }
}

// ---------------------------------------------------------------------------
// 3x3 grouped quaternion conv + residual add.
// ---------------------------------------------------------------------------
__global__ __launch_bounds__(256) void pe_conv_kernel(
    const float* __restrict__ x,
    const float* __restrict__ w,
    const float* __restrict__ bias,
    float* __restrict__ y)
{
    const int bid = blockIdx.x;
    const int pt = bid & 3, co = (bid >> 2) & 63, b = bid >> 8;
    const int p = (pt << 8) + threadIdx.x;
    const int hh = p >> 5, ww = p & 31;
    const int g4 = (co >> 2) << 2;

    float a0 = bias[co * 4 + 0], a1 = bias[co * 4 + 1];
    float a2 = bias[co * 4 + 2], a3 = bias[co * 4 + 3];
    const float* xb = x + (size_t)b * 64 * 4096;
    const float* wb = w + co * 36;

#pragma unroll
    for (int dy = 0; dy < 3; dy++) {
        int yy = hh + dy - 1;
        if ((unsigned)yy >= 32u) continue;
#pragma unroll
        for (int dx = 0; dx < 3; dx++) {
            int xx = ww + dx - 1;
            if ((unsigned)xx >= 32u) continue;
            int sp = yy * 32 + xx;
#pragma unroll
            for (int cl = 0; cl < 4; cl++) {
                const float* xp = xb + (size_t)(g4 + cl) * 4096 + sp;
                float xr = xp[0], xi = xp[1024], xj = xp[2048], xk = xp[3072];
                const float* wp = wb + cl * 9 + dy * 3 + dx;
                float wr = wp[0], wi = wp[2304], wj2 = wp[4608], wk = wp[6912];
                a0 += xr * wr - xi * wi  - xj * wj2 - xk * wk;
                a1 += xr * wi + xi * wr  + xj * wk  - xk * wj2;
                a2 += xr * wj2 - xi * wk + xj * wr  + xk * wi;
                a3 += xr * wk + xi * wj2 - xj * wi  + xk * wr;
            }
        }
    }
    size_t ob = (size_t)b * 64 * 4096 + (size_t)co * 4096 + p;
    y[ob]        = x[ob]        + a0;
    y[ob + 1024] = x[ob + 1024] + a1;
    y[ob + 2048] = x[ob + 2048] + a2;
    y[ob + 3072] = x[ob + 3072] + a3;
}

// ---------------------------------------------------------------------------
extern "C" void kernel_launch(void* const* d_in, const int* in_sizes, int n_in,
                              void* d_out, int out_size, void* d_ws, size_t ws_size,
                              hipStream_t stream)
{
    const float* x      = (const float*)d_in[0];
    const float* cv1_w  = (const float*)d_in[1];
    const float* bn1_g  = (const float*)d_in[2];
    const float* bn1_b  = (const float*)d_in[3];
    const float* qkv_w  = (const float*)d_in[4];
    const float* qkv_b  = (const float*)d_in[5];
    const float* proj_w = (const float*)d_in[6];
    const float* proj_b = (const float*)d_in[7];
    const float* pe_w   = (const float*)d_in[8];
    const float* pe_b   = (const float*)d_in[9];
    const float* ang    = (const float*)d_in[10];
    const float* anb    = (const float*)d_in[11];
    const float* ffn1_w = (const float*)d_in[12];
    const float* fbn1_g = (const float*)d_in[13];
    const float* fbn1_b = (const float*)d_in[14];
    const float* ffn2_w = (const float*)d_in[15];
    const float* fbn2_g = (const float*)d_in[16];
    const float* fbn2_b = (const float*)d_in[17];
    const float* cv2_w  = (const float*)d_in[18];
    const float* bn2_g  = (const float*)d_in[19];
    const float* bn2_b  = (const float*)d_in[20];
    float* out = (float*)d_out;

    float* ws    = (float*)d_ws;
    float* hbuf  = ws;                       // [4,128,4,1024]
    float* qkvb  = ws + 2097152;             // [4,192,4,1024]
    float* bufA  = ws + 5242880;             // [4,64,4,1024]
    float* bufD  = ws + 6291456;             // [4,128,4,1024]
    float* stats = ws + 8388608;             // 1024
    ushort* Xp   = (ushort*)(ws + 8389632);  // up to 4096x512 bf16
    ushort* Wx   = (ushort*)(ws + 9438208);  // up to 512x512 bf16
    float* bufB  = qkvb;                     // alias (qkv dead after attn)
    float* bufC  = qkvb + 1048576;           // alias
    float* cv2o  = qkvb;                     // alias

    const int S128 = 128 * 4096, S192 = 192 * 4096, S64 = 64 * 4096;

    // 1. cv1 (512x4096x512) + iqbn + relu -> hbuf
    wexpand_kernel<<<1024, 256, 0, stream>>>(cv1_w, Wx, 128, 128);
    pack_kernel<<<dim3(16, 16), 256, 0, stream>>>(x, S128, Xp, 512);
    qgemm_kernel<<<dim3(8, 32), 256, 0, stream>>>(Xp, Wx, nullptr, hbuf, S128, 512, 512);
    iqbn_stats_kernel<<<512, 256, 0, stream>>>(hbuf, S128, stats);
    iqbn_apply_kernel<<<2048, 256, 0, stream>>>(hbuf, S128, hbuf, S128, stats, bn1_g, bn1_b, 512, 1);

    // 2. qkv (768x4096x256, a-half input) -> qkvb
    wexpand_kernel<<<768, 256, 0, stream>>>(qkv_w, Wx, 192, 64);
    pack_kernel<<<dim3(8, 16), 256, 0, stream>>>(hbuf, S128, Xp, 256);
    qgemm_kernel<<<dim3(12, 32), 256, 0, stream>>>(Xp, Wx, qkv_b, qkvb, S192, 768, 256);

    // 3. attention (MFMA flash) -> bufA
    qattn_kernel<<<dim3(64, 8), 256, 0, stream>>>(qkvb, bufA);

    // 4. pe conv + residual -> bufB
    pe_conv_kernel<<<1024, 256, 0, stream>>>(bufA, pe_w, pe_b, bufB);

    // 5. proj (256x4096x256) -> bufC ; iqbn
    wexpand_kernel<<<256, 256, 0, stream>>>(proj_w, Wx, 64, 64);
    pack_kernel<<<dim3(8, 16), 256, 0, stream>>>(bufB, S64, Xp, 256);
    qgemm_kernel<<<dim3(4, 32), 256, 0, stream>>>(Xp, Wx, proj_b, bufC, S64, 256, 256);
    iqbn_stats_kernel<<<256, 256, 0, stream>>>(bufC, S64, stats);
    iqbn_apply_kernel<<<1024, 256, 0, stream>>>(bufC, S64, bufC, S64, stats, ang, anb, 256, 0);

    // 6. ffn1 (512x4096x256) -> bufD ; iqbn + relu
    wexpand_kernel<<<512, 256, 0, stream>>>(ffn1_w, Wx, 128, 64);
    pack_kernel<<<dim3(8, 16), 256, 0, stream>>>(bufC, S64, Xp, 256);
    qgemm_kernel<<<dim3(8, 32), 256, 0, stream>>>(Xp, Wx, nullptr, bufD, S128, 512, 256);
    iqbn_stats_kernel<<<512, 256, 0, stream>>>(bufD, S128, stats);
    iqbn_apply_kernel<<<2048, 256, 0, stream>>>(bufD, S128, bufD, S128, stats, fbn1_g, fbn1_b, 512, 1);

    // 7. ffn2 (256x4096x512) -> bufA ; iqbn -> hbuf[:, :64] (free concat)
    wexpand_kernel<<<512, 256, 0, stream>>>(ffn2_w, Wx, 64, 128);
    pack_kernel<<<dim3(16, 16), 256, 0, stream>>>(bufD, S128, Xp, 512);
    qgemm_kernel<<<dim3(4, 32), 256, 0, stream>>>(Xp, Wx, nullptr, bufA, S64, 256, 512);
    iqbn_stats_kernel<<<256, 256, 0, stream>>>(bufA, S64, stats);
    iqbn_apply_kernel<<<1024, 256, 0, stream>>>(bufA, S64, hbuf, S128, stats, fbn2_g, fbn2_b, 256, 0);

    // 8. cv2 (512x4096x512) -> cv2o ; iqbn + relu -> out
    wexpand_kernel<<<1024, 256, 0, stream>>>(cv2_w, Wx, 128, 128);
    pack_kernel<<<dim3(16, 16), 256, 0, stream>>>(hbuf, S128, Xp, 512);
    qgemm_kernel<<<dim3(8, 32), 256, 0, stream>>>(Xp, Wx, nullptr, cv2o, S128, 512, 512);
    iqbn_stats_kernel<<<512, 256, 0, stream>>>(cv2o, S128, stats);
    iqbn_apply_kernel<<<2048, 256, 0, stream>>>(cv2o, S128, out, S128, stats, bn2_g, bn2_b, 512, 1);
}